// Round 8
// baseline (159.638 us; speedup 1.0000x reference)
//
#include <hip/hip_runtime.h>
#include <hip/hip_bf16.h>

#define D_FEAT 128
#define PAD 64          // padded slots per node; avg degree 12, P(>64) ~ 1e-20
#define OVF_CAP 4096    // overflow side-list capacity (expected use: 0)

// ======================= FAST PATH: padded buckets =======================

// Bucket edges into pairs[dst*PAD + pos]; cursor[dst] ends up = degree.
__global__ void bucket_pad_kernel(const int* __restrict__ src, const int* __restrict__ dst,
                                  const float* __restrict__ dt, const float* __restrict__ norm,
                                  const float* __restrict__ decay_lam,
                                  int* __restrict__ cursor, float2* __restrict__ pairs,
                                  int* __restrict__ ovf_cnt, int* __restrict__ ovf_d,
                                  int* __restrict__ ovf_s, float* __restrict__ ovf_w, int E) {
    int e = blockIdx.x * blockDim.x + threadIdx.x;
    if (e >= E) return;
    float lam = fmaxf(decay_lam[0], 0.0f) + 1e-4f;
    float w = norm[e] * expf(-lam * dt[e]);
    int d = dst[e];
    int s = src[e];
    int pos = atomicAdd(&cursor[d], 1);
    if (pos < PAD) {
        float2 p;
        p.x = __int_as_float(s);
        p.y = w;
        pairs[(size_t)d * PAD + pos] = p;
    } else {
        int o = atomicAdd(ovf_cnt, 1);
        if (o < OVF_CAP) { ovf_d[o] = d; ovf_s[o] = s; ovf_w[o] = w; }
    }
}

// One wave per node; lane holds float2 of the feature row.
// r7: bulk-load pairs once, shfl-broadcast, unroll-4.
// r8: lanes >= m hold (src=0, w=0), so round trip count to a multiple of 8 and
// drop the tail entirely — fake edges gather L1-hot row 0 with weight 0.
// 8 independent 512 B row loads in flight per body.
__global__ void __launch_bounds__(256)
gather_pad_kernel(const float* __restrict__ h, const int* __restrict__ cursor,
                  const float2* __restrict__ pairs,
                  const int* __restrict__ ovf_cnt, const int* __restrict__ ovf_d,
                  const int* __restrict__ ovf_s, const float* __restrict__ ovf_w,
                  float* __restrict__ out, int N) {
    int node = blockIdx.x * 4 + (threadIdx.x >> 6);
    if (node >= N) return;
    int lane = threadIdx.x & 63;
    int deg = cursor[node];
    int m = min(deg, PAD);
    const float2* row = pairs + (size_t)node * PAD;

    // one vector load grabs this node's whole edge list across lanes;
    // lanes >= m keep (0, 0.0f) which makes padded iterations no-ops
    float2 p = make_float2(0.0f, 0.0f);
    if (lane < m) p = row[lane];
    int   psrc = __float_as_int(p.x);
    float pw   = p.y;

    int mr = (m + 7) & ~7;  // <= PAD = 64, shfl indices stay in range

    float accx = 0.0f, accy = 0.0f;
    for (int j = 0; j < mr; j += 8) {
        int   s0 = __shfl(psrc, j + 0, 64);  float w0 = __shfl(pw, j + 0, 64);
        int   s1 = __shfl(psrc, j + 1, 64);  float w1 = __shfl(pw, j + 1, 64);
        int   s2 = __shfl(psrc, j + 2, 64);  float w2 = __shfl(pw, j + 2, 64);
        int   s3 = __shfl(psrc, j + 3, 64);  float w3 = __shfl(pw, j + 3, 64);
        int   s4 = __shfl(psrc, j + 4, 64);  float w4 = __shfl(pw, j + 4, 64);
        int   s5 = __shfl(psrc, j + 5, 64);  float w5 = __shfl(pw, j + 5, 64);
        int   s6 = __shfl(psrc, j + 6, 64);  float w6 = __shfl(pw, j + 6, 64);
        int   s7 = __shfl(psrc, j + 7, 64);  float w7 = __shfl(pw, j + 7, 64);
        float2 v0 = ((const float2*)(h + (size_t)s0 * D_FEAT))[lane];
        float2 v1 = ((const float2*)(h + (size_t)s1 * D_FEAT))[lane];
        float2 v2 = ((const float2*)(h + (size_t)s2 * D_FEAT))[lane];
        float2 v3 = ((const float2*)(h + (size_t)s3 * D_FEAT))[lane];
        float2 v4 = ((const float2*)(h + (size_t)s4 * D_FEAT))[lane];
        float2 v5 = ((const float2*)(h + (size_t)s5 * D_FEAT))[lane];
        float2 v6 = ((const float2*)(h + (size_t)s6 * D_FEAT))[lane];
        float2 v7 = ((const float2*)(h + (size_t)s7 * D_FEAT))[lane];
        accx += v0.x * w0; accy += v0.y * w0;
        accx += v1.x * w1; accy += v1.y * w1;
        accx += v2.x * w2; accy += v2.y * w2;
        accx += v3.x * w3; accy += v3.y * w3;
        accx += v4.x * w4; accy += v4.y * w4;
        accx += v5.x * w5; accy += v5.y * w5;
        accx += v6.x * w6; accy += v6.y * w6;
        accx += v7.x * w7; accy += v7.y * w7;
    }

    if (deg > PAD) {  // only overflowing nodes scan the side list (expected: never)
        int oc = min(*ovf_cnt, OVF_CAP);
        for (int o = 0; o < oc; ++o) {
            if (ovf_d[o] == node) {
                float we = ovf_w[o];
                float2 v = ((const float2*)(h + (size_t)ovf_s[o] * D_FEAT))[lane];
                accx += v.x * we;
                accy += v.y * we;
            }
        }
    }
    float2 r; r.x = accx; r.y = accy;
    ((float2*)(out + (size_t)node * D_FEAT))[lane] = r;
}

// ================== FALLBACK PATH: compact CSR (round-2) ==================

__global__ void degree_kernel(const int* __restrict__ dst, int* __restrict__ deg, int E) {
    int e = blockIdx.x * blockDim.x + threadIdx.x;
    if (e >= E) return;
    atomicAdd(&deg[dst[e]], 1);
}

__global__ void scan_blocks(const int* __restrict__ deg, int* __restrict__ offs,
                            int* __restrict__ blockSums, int N) {
    __shared__ int tmp[256];
    int tid = threadIdx.x;
    int gid = blockIdx.x * 256 + tid;
    int v = (gid < N) ? deg[gid] : 0;
    tmp[tid] = v;
    __syncthreads();
    for (int off = 1; off < 256; off <<= 1) {
        int t = (tid >= off) ? tmp[tid - off] : 0;
        __syncthreads();
        tmp[tid] += t;
        __syncthreads();
    }
    if (gid < N) offs[gid] = tmp[tid] - v;
    if (tid == 255) blockSums[blockIdx.x] = tmp[255];
}

__global__ void scan_sums(int* __restrict__ blockSums, int* __restrict__ blockOffs, int nb) {
    __shared__ int tmp[256];
    int tid = threadIdx.x;
    int v = (tid < nb) ? blockSums[tid] : 0;
    tmp[tid] = v;
    __syncthreads();
    for (int off = 1; off < 256; off <<= 1) {
        int t = (tid >= off) ? tmp[tid - off] : 0;
        __syncthreads();
        tmp[tid] += t;
        __syncthreads();
    }
    if (tid < nb) blockOffs[tid] = tmp[tid] - v;
}

__global__ void scan_fixup(int* __restrict__ offs, const int* __restrict__ blockOffs,
                           int* __restrict__ cursor, int N) {
    int gid = blockIdx.x * 256 + threadIdx.x;
    if (gid >= N) return;
    int o = offs[gid] + blockOffs[blockIdx.x];
    offs[gid] = o;
    cursor[gid] = o;
}

__global__ void bucket_kernel(const int* __restrict__ src, const int* __restrict__ dst,
                              const float* __restrict__ dt, const float* __restrict__ norm,
                              const float* __restrict__ decay_lam,
                              int* __restrict__ cursor, float2* __restrict__ pairs, int E) {
    int e = blockIdx.x * blockDim.x + threadIdx.x;
    if (e >= E) return;
    float lam = fmaxf(decay_lam[0], 0.0f) + 1e-4f;
    float w = norm[e] * expf(-lam * dt[e]);
    int d = dst[e];
    int pos = atomicAdd(&cursor[d], 1);
    float2 p;
    p.x = __int_as_float(src[e]);
    p.y = w;
    pairs[pos] = p;
}

__global__ void __launch_bounds__(256)
gather_kernel(const float* __restrict__ h,
              const int* __restrict__ offs, const int* __restrict__ deg,
              const float2* __restrict__ pairs, float* __restrict__ out, int N) {
    int node = blockIdx.x * 4 + (threadIdx.x >> 6);
    if (node >= N) return;
    int lane = threadIdx.x & 63;
    int start = offs[node];
    int end = start + deg[node];
    float accx = 0.0f, accy = 0.0f;
    for (int j = start; j < end; ++j) {
        float2 p = pairs[j];
        int s = __float_as_int(p.x);
        float we = p.y;
        float2 v = ((const float2*)(h + (size_t)s * D_FEAT))[lane];
        accx += v.x * we;
        accy += v.y * we;
    }
    float2 r; r.x = accx; r.y = accy;
    ((float2*)(out + (size_t)node * D_FEAT))[lane] = r;
}

extern "C" void kernel_launch(void* const* d_in, const int* in_sizes, int n_in,
                              void* d_out, int out_size, void* d_ws, size_t ws_size,
                              hipStream_t stream) {
    const float* h         = (const float*)d_in[0];
    const int*   src       = (const int*)d_in[1];
    const int*   dst       = (const int*)d_in[2];
    const float* dt        = (const float*)d_in[3];
    const float* norm      = (const float*)d_in[4];
    const float* decay_lam = (const float*)d_in[5];
    float* out = (float*)d_out;

    const int E = in_sizes[1];
    const int N = out_size / D_FEAT;

    size_t pad_need = (size_t)N * 4            // cursor
                    + 64                       // ovf counter (padded)
                    + (size_t)OVF_CAP * 12     // ovf lists
                    + (size_t)N * PAD * 8;     // padded pairs

    if (ws_size >= pad_need) {
        // -------- fast path: 1 memset + 2 kernels --------
        char* ws = (char*)d_ws;
        int*    cursor  = (int*)ws;    ws += (size_t)N * 4;
        int*    ovf_cnt = (int*)ws;    ws += 64;
        int*    ovf_d   = (int*)ws;    ws += (size_t)OVF_CAP * 4;
        int*    ovf_s   = (int*)ws;    ws += (size_t)OVF_CAP * 4;
        float*  ovf_w   = (float*)ws;  ws += (size_t)OVF_CAP * 4;
        float2* pairs   = (float2*)ws;

        // zero cursor + ovf counter in one contiguous memset
        hipMemsetAsync(cursor, 0, (size_t)N * 4 + 64, stream);

        bucket_pad_kernel<<<(E + 255) / 256, 256, 0, stream>>>(
            src, dst, dt, norm, decay_lam, cursor, pairs,
            ovf_cnt, ovf_d, ovf_s, ovf_w, E);

        gather_pad_kernel<<<(N + 3) / 4, 256, 0, stream>>>(
            h, cursor, pairs, ovf_cnt, ovf_d, ovf_s, ovf_w, out, N);
    } else {
        // -------- fallback: compact CSR with hierarchical scan --------
        const int nb = (N + 255) / 256;
        char* ws = (char*)d_ws;
        int*    deg       = (int*)ws;     ws += (size_t)N * 4;
        int*    offs      = (int*)ws;     ws += (size_t)N * 4;
        int*    cursor    = (int*)ws;     ws += (size_t)N * 4;
        int*    blockSums = (int*)ws;     ws += 256 * 4;
        int*    blockOffs = (int*)ws;     ws += 256 * 4;
        float2* pairs     = (float2*)ws;

        hipMemsetAsync(deg, 0, (size_t)N * 4, stream);
        degree_kernel<<<(E + 255) / 256, 256, 0, stream>>>(dst, deg, E);
        scan_blocks<<<nb, 256, 0, stream>>>(deg, offs, blockSums, N);
        scan_sums<<<1, 256, 0, stream>>>(blockSums, blockOffs, nb);
        scan_fixup<<<nb, 256, 0, stream>>>(offs, blockOffs, cursor, N);
        bucket_kernel<<<(E + 255) / 256, 256, 0, stream>>>(
            src, dst, dt, norm, decay_lam, cursor, pairs, E);
        gather_kernel<<<(N + 3) / 4, 256, 0, stream>>>(h, offs, deg, pairs, out, N);
    }
}

// Round 10
// 156.105 us; speedup vs baseline: 1.0226x; 1.0226x over previous
//
#include <hip/hip_runtime.h>
#include <hip/hip_bf16.h>

#define D_FEAT 128
#define PAD 32          // padded slots per node; Poisson(12), P(deg>32) ~ 1e-7/node
#define OVF_CAP 4096    // overflow side-list capacity (expected use: 0)

typedef float f2v __attribute__((ext_vector_type(2)));  // builtin-compatible vec2

// round-to-nearest-even fp32 -> bf16 bits
__device__ __forceinline__ unsigned bf16_rne(float f) {
    unsigned u = __float_as_uint(f);
    return (u + 0x7fffu + ((u >> 16) & 1u)) >> 16;
}

// ============== FAST PATH: fused bf16-convert + padded bucket ==============
// Block range [0, convBlocks): convert h (fp32) -> hb (bf16), 4 feats/thread.
// Block range [convBlocks, ...): bucket edges into pairs[dst*PAD + pos] as
// packed 4 B entries (src:16 | bf16(w):16); cursor[dst] ends up = degree.
__global__ void conv_bucket_kernel(const float* __restrict__ h,
                                   const int* __restrict__ src, const int* __restrict__ dst,
                                   const float* __restrict__ dt, const float* __restrict__ norm,
                                   const float* __restrict__ decay_lam,
                                   unsigned* __restrict__ hb,      // bf16-pair packed h
                                   int* __restrict__ cursor, unsigned* __restrict__ pairs,
                                   int* __restrict__ ovf_cnt, int* __restrict__ ovf_d,
                                   int* __restrict__ ovf_s, float* __restrict__ ovf_w,
                                   int E, int HN4, int convBlocks) {
    int bid = blockIdx.x;
    if (bid < convBlocks) {
        int i = bid * 256 + threadIdx.x;
        if (i < HN4) {
            float4 v = ((const float4*)h)[i];
            unsigned lo = bf16_rne(v.x) | (bf16_rne(v.y) << 16);
            unsigned hi = bf16_rne(v.z) | (bf16_rne(v.w) << 16);
            ((uint2*)hb)[i] = make_uint2(lo, hi);
        }
    } else {
        int e = (bid - convBlocks) * 256 + threadIdx.x;
        if (e >= E) return;
        float lam = fmaxf(decay_lam[0], 0.0f) + 1e-4f;
        float w = norm[e] * expf(-lam * dt[e]);
        int d = dst[e];
        int s = src[e];
        int pos = atomicAdd(&cursor[d], 1);
        if (pos < PAD) {
            pairs[(size_t)d * PAD + pos] = ((unsigned)s << 16) | bf16_rne(w);
        } else {
            int o = atomicAdd(ovf_cnt, 1);
            if (o < OVF_CAP) { ovf_d[o] = d; ovf_s[o] = s; ovf_w[o] = w; }
        }
    }
}

// One wave per node. Lane covers feats (2*lane, 2*lane+1) as one packed uint.
// Pairs bulk-loaded once (lanes >= m hold 0 => src 0, w +0.0f: no-op edges);
// trip count rounded to multiple of 8, 8 independent 256 B row loads in flight.
__global__ void __launch_bounds__(256)
gather_pad_kernel(const unsigned* __restrict__ hb, const int* __restrict__ cursor,
                  const unsigned* __restrict__ pairs,
                  const int* __restrict__ ovf_cnt, const int* __restrict__ ovf_d,
                  const int* __restrict__ ovf_s, const float* __restrict__ ovf_w,
                  float* __restrict__ out, int N) {
    int node = blockIdx.x * 4 + (threadIdx.x >> 6);
    if (node >= N) return;
    int lane = threadIdx.x & 63;
    int deg = cursor[node];
    int m = min(deg, PAD);

    unsigned pu = 0;
    if (lane < m) pu = pairs[(size_t)node * PAD + lane];

    int mr = (m + 7) & ~7;  // <= PAD = 32; shfl indices stay in lane range

    float accx = 0.0f, accy = 0.0f;
    for (int j = 0; j < mr; j += 8) {
        unsigned u0 = __shfl(pu, j + 0, 64);
        unsigned u1 = __shfl(pu, j + 1, 64);
        unsigned u2 = __shfl(pu, j + 2, 64);
        unsigned u3 = __shfl(pu, j + 3, 64);
        unsigned u4 = __shfl(pu, j + 4, 64);
        unsigned u5 = __shfl(pu, j + 5, 64);
        unsigned u6 = __shfl(pu, j + 6, 64);
        unsigned u7 = __shfl(pu, j + 7, 64);
        unsigned v0 = hb[(size_t)(u0 >> 16) * 64 + lane];
        unsigned v1 = hb[(size_t)(u1 >> 16) * 64 + lane];
        unsigned v2 = hb[(size_t)(u2 >> 16) * 64 + lane];
        unsigned v3 = hb[(size_t)(u3 >> 16) * 64 + lane];
        unsigned v4 = hb[(size_t)(u4 >> 16) * 64 + lane];
        unsigned v5 = hb[(size_t)(u5 >> 16) * 64 + lane];
        unsigned v6 = hb[(size_t)(u6 >> 16) * 64 + lane];
        unsigned v7 = hb[(size_t)(u7 >> 16) * 64 + lane];
        #define ACC(u, v)                                             \
        {   float wf = __uint_as_float((u) << 16);                    \
            float vx = __uint_as_float((v) << 16);                    \
            float vy = __uint_as_float((v) & 0xffff0000u);            \
            accx += vx * wf; accy += vy * wf; }
        ACC(u0, v0) ACC(u1, v1) ACC(u2, v2) ACC(u3, v3)
        ACC(u4, v4) ACC(u5, v5) ACC(u6, v6) ACC(u7, v7)
        #undef ACC
    }

    if (deg > PAD) {  // only overflowing nodes scan the side list (expected: never)
        int oc = min(*ovf_cnt, OVF_CAP);
        for (int o = 0; o < oc; ++o) {
            if (ovf_d[o] == node) {
                float we = ovf_w[o];
                unsigned v = hb[(size_t)ovf_s[o] * 64 + lane];
                accx += __uint_as_float(v << 16) * we;
                accy += __uint_as_float(v & 0xffff0000u) * we;
            }
        }
    }
    f2v r;
    r.x = accx; r.y = accy;
    __builtin_nontemporal_store(r, (f2v*)(out + (size_t)node * D_FEAT) + lane);
}

// ================== FALLBACK PATH: compact CSR (fp32, exact) ==================

__global__ void degree_kernel(const int* __restrict__ dst, int* __restrict__ deg, int E) {
    int e = blockIdx.x * blockDim.x + threadIdx.x;
    if (e >= E) return;
    atomicAdd(&deg[dst[e]], 1);
}

__global__ void scan_blocks(const int* __restrict__ deg, int* __restrict__ offs,
                            int* __restrict__ blockSums, int N) {
    __shared__ int tmp[256];
    int tid = threadIdx.x;
    int gid = blockIdx.x * 256 + tid;
    int v = (gid < N) ? deg[gid] : 0;
    tmp[tid] = v;
    __syncthreads();
    for (int off = 1; off < 256; off <<= 1) {
        int t = (tid >= off) ? tmp[tid - off] : 0;
        __syncthreads();
        tmp[tid] += t;
        __syncthreads();
    }
    if (gid < N) offs[gid] = tmp[tid] - v;
    if (tid == 255) blockSums[blockIdx.x] = tmp[255];
}

__global__ void scan_sums(int* __restrict__ blockSums, int* __restrict__ blockOffs, int nb) {
    __shared__ int tmp[256];
    int tid = threadIdx.x;
    int v = (tid < nb) ? blockSums[tid] : 0;
    tmp[tid] = v;
    __syncthreads();
    for (int off = 1; off < 256; off <<= 1) {
        int t = (tid >= off) ? tmp[tid - off] : 0;
        __syncthreads();
        tmp[tid] += t;
        __syncthreads();
    }
    if (tid < nb) blockOffs[tid] = tmp[tid] - v;
}

__global__ void scan_fixup(int* __restrict__ offs, const int* __restrict__ blockOffs,
                           int* __restrict__ cursor, int N) {
    int gid = blockIdx.x * 256 + threadIdx.x;
    if (gid >= N) return;
    int o = offs[gid] + blockOffs[blockIdx.x];
    offs[gid] = o;
    cursor[gid] = o;
}

__global__ void bucket_kernel(const int* __restrict__ src, const int* __restrict__ dst,
                              const float* __restrict__ dt, const float* __restrict__ norm,
                              const float* __restrict__ decay_lam,
                              int* __restrict__ cursor, float2* __restrict__ pairs, int E) {
    int e = blockIdx.x * blockDim.x + threadIdx.x;
    if (e >= E) return;
    float lam = fmaxf(decay_lam[0], 0.0f) + 1e-4f;
    float w = norm[e] * expf(-lam * dt[e]);
    int d = dst[e];
    int pos = atomicAdd(&cursor[d], 1);
    float2 p;
    p.x = __int_as_float(src[e]);
    p.y = w;
    pairs[pos] = p;
}

__global__ void __launch_bounds__(256)
gather_kernel(const float* __restrict__ h,
              const int* __restrict__ offs, const int* __restrict__ deg,
              const float2* __restrict__ pairs, float* __restrict__ out, int N) {
    int node = blockIdx.x * 4 + (threadIdx.x >> 6);
    if (node >= N) return;
    int lane = threadIdx.x & 63;
    int start = offs[node];
    int end = start + deg[node];
    float accx = 0.0f, accy = 0.0f;
    for (int j = start; j < end; ++j) {
        float2 p = pairs[j];
        int s = __float_as_int(p.x);
        float we = p.y;
        float2 v = ((const float2*)(h + (size_t)s * D_FEAT))[lane];
        accx += v.x * we;
        accy += v.y * we;
    }
    float2 r; r.x = accx; r.y = accy;
    ((float2*)(out + (size_t)node * D_FEAT))[lane] = r;
}

extern "C" void kernel_launch(void* const* d_in, const int* in_sizes, int n_in,
                              void* d_out, int out_size, void* d_ws, size_t ws_size,
                              hipStream_t stream) {
    const float* h         = (const float*)d_in[0];
    const int*   src       = (const int*)d_in[1];
    const int*   dst       = (const int*)d_in[2];
    const float* dt        = (const float*)d_in[3];
    const float* norm      = (const float*)d_in[4];
    const float* decay_lam = (const float*)d_in[5];
    float* out = (float*)d_out;

    const int E  = in_sizes[1];
    const int HN = in_sizes[0];          // total h elements
    const int N  = out_size / D_FEAT;

    size_t pad_need = (size_t)N * 4            // cursor
                    + 64                       // ovf counter (padded)
                    + (size_t)OVF_CAP * 12     // ovf lists
                    + (size_t)N * PAD * 4      // packed pairs
                    + (size_t)HN * 2;          // bf16 h

    if (ws_size >= pad_need && N <= 65536 && (HN & 3) == 0) {
        // -------- fast path: 1 memset + 2 kernels --------
        char* ws = (char*)d_ws;
        int*      cursor  = (int*)ws;       ws += (size_t)N * 4;
        int*      ovf_cnt = (int*)ws;       ws += 64;
        int*      ovf_d   = (int*)ws;       ws += (size_t)OVF_CAP * 4;
        int*      ovf_s   = (int*)ws;       ws += (size_t)OVF_CAP * 4;
        float*    ovf_w   = (float*)ws;     ws += (size_t)OVF_CAP * 4;
        unsigned* pairs   = (unsigned*)ws;  ws += (size_t)N * PAD * 4;
        unsigned* hb      = (unsigned*)ws;

        // zero cursor + ovf counter in one contiguous memset
        hipMemsetAsync(cursor, 0, (size_t)N * 4 + 64, stream);

        const int HN4 = HN / 4;
        const int convBlocks = (HN4 + 255) / 256;
        const int bucketBlocks = (E + 255) / 256;
        conv_bucket_kernel<<<convBlocks + bucketBlocks, 256, 0, stream>>>(
            h, src, dst, dt, norm, decay_lam, hb, cursor, pairs,
            ovf_cnt, ovf_d, ovf_s, ovf_w, E, HN4, convBlocks);

        gather_pad_kernel<<<(N + 3) / 4, 256, 0, stream>>>(
            hb, cursor, pairs, ovf_cnt, ovf_d, ovf_s, ovf_w, out, N);
    } else {
        // -------- fallback: compact CSR with hierarchical scan (fp32 exact) --------
        const int nb = (N + 255) / 256;
        char* ws = (char*)d_ws;
        int*    deg       = (int*)ws;     ws += (size_t)N * 4;
        int*    offs      = (int*)ws;     ws += (size_t)N * 4;
        int*    cursor    = (int*)ws;     ws += (size_t)N * 4;
        int*    blockSums = (int*)ws;     ws += 256 * 4;
        int*    blockOffs = (int*)ws;     ws += 256 * 4;
        float2* pairs     = (float2*)ws;

        hipMemsetAsync(deg, 0, (size_t)N * 4, stream);
        degree_kernel<<<(E + 255) / 256, 256, 0, stream>>>(dst, deg, E);
        scan_blocks<<<nb, 256, 0, stream>>>(deg, offs, blockSums, N);
        scan_sums<<<1, 256, 0, stream>>>(blockSums, blockOffs, nb);
        scan_fixup<<<nb, 256, 0, stream>>>(offs, blockOffs, cursor, N);
        bucket_kernel<<<(E + 255) / 256, 256, 0, stream>>>(
            src, dst, dt, norm, decay_lam, cursor, pairs, E);
        gather_kernel<<<(N + 3) / 4, 256, 0, stream>>>(h, offs, deg, pairs, out, N);
    }
}

// Round 11
// 130.465 us; speedup vs baseline: 1.2236x; 1.1965x over previous
//
#include <hip/hip_runtime.h>
#include <hip/hip_bf16.h>

#define D_FEAT 128
#define BIN_SHIFT 7
#define NODES_PER_BIN 128      // bin = node >> 7
#define BCAP 4096              // entries per bin region; avg ~1536 at E=600k,N=50k
#define EPB 4096               // edges per bin_kernel block
#define T1 512
#define OVF_CAP 4096           // overflow side-list (expected use: 0)

typedef float f2v __attribute__((ext_vector_type(2)));

// round-to-nearest-even fp32 -> bf16 bits
__device__ __forceinline__ unsigned bf16_rne(float f) {
    unsigned u = __float_as_uint(f);
    return (u + 0x7fffu + ((u >> 16) & 1u)) >> 16;
}

// ---- fast path kernel 1: h (fp32) -> hb (packed bf16 pairs), streaming ----
__global__ void conv_kernel(const float* __restrict__ h, unsigned* __restrict__ hb, int HN4) {
    int i = blockIdx.x * 256 + threadIdx.x;
    if (i >= HN4) return;
    float4 v = ((const float4*)h)[i];
    ((uint2*)hb)[i] = make_uint2(bf16_rne(v.x) | (bf16_rne(v.y) << 16),
                                 bf16_rne(v.z) | (bf16_rne(v.w) << 16));
}

// ---- fast path kernel 2: LDS-grouped binning by dst>>7 ----
// Entry: hi32 = local node (dst & 127), lo32 = (src<<16) | bf16(w).
// Per-edge global scatter replaced by: LDS histogram + scan + LDS reorder,
// one global cursor atomic per (block,bin), grouped ~84 B streaming runs.
__global__ void __launch_bounds__(T1)
bin_kernel(const int* __restrict__ src, const int* __restrict__ dst,
           const float* __restrict__ dt, const float* __restrict__ norm,
           const float* __restrict__ decay_lam,
           int* __restrict__ bin_cursor, unsigned long long* __restrict__ binned,
           int* __restrict__ ovf_cnt, int* __restrict__ ovf_d,
           int* __restrict__ ovf_s, float* __restrict__ ovf_w,
           int E, int NB) {
    __shared__ unsigned hist[T1];
    __shared__ unsigned tmp[T1];
    __shared__ unsigned cur[T1];
    __shared__ unsigned gbase[T1];
    __shared__ unsigned long long stage[EPB];
    __shared__ unsigned gaddr[EPB];

    int t = threadIdx.x;
    int e0 = blockIdx.x * EPB;
    int cnt_blk = min(EPB, E - e0);

    hist[t] = 0; cur[t] = 0; gbase[t] = 0;
    __syncthreads();

    float lam = fmaxf(decay_lam[0], 0.0f) + 1e-4f;

    unsigned long long ent[EPB / T1];
    int bn[EPB / T1];
    #pragma unroll
    for (int k = 0; k < EPB / T1; ++k) {
        int e = e0 + k * T1 + t;
        bn[k] = -1;
        if (e < E) {
            int s = src[e], d = dst[e];
            float w = norm[e] * expf(-lam * dt[e]);
            int b = d >> BIN_SHIFT;
            int l = d & (NODES_PER_BIN - 1);
            ent[k] = ((unsigned long long)l << 32) | (((unsigned)s << 16) | bf16_rne(w));
            bn[k] = b;
            atomicAdd(&hist[b], 1u);
        }
    }
    __syncthreads();
    tmp[t] = hist[t];
    __syncthreads();
    for (int off = 1; off < T1; off <<= 1) {       // inclusive scan
        unsigned v = (t >= off) ? tmp[t - off] : 0;
        __syncthreads();
        tmp[t] += v;
        __syncthreads();
    }
    unsigned base_t = tmp[t] - hist[t];            // exclusive prefix (stage base)
    if (t < NB && hist[t] > 0)
        gbase[t] = (unsigned)atomicAdd(&bin_cursor[t], (int)hist[t]);
    __syncthreads();
    tmp[t] = base_t;                               // tmp now = per-bin stage base
    __syncthreads();

    #pragma unroll
    for (int k = 0; k < EPB / T1; ++k) {
        if (bn[k] >= 0) {
            int b = bn[k];
            unsigned loc = atomicAdd(&cur[b], 1u);
            unsigned p = tmp[b] + loc;             // stage position (grouped by bin)
            unsigned gp = gbase[b] + loc;          // position within bin region
            stage[p] = ent[k];
            if (gp < BCAP) {
                gaddr[p] = (unsigned)b * BCAP + gp;
            } else {                               // bin region full (expected: never)
                gaddr[p] = 0xFFFFFFFFu;
                int o = atomicAdd(ovf_cnt, 1);
                if (o < OVF_CAP) {
                    int l = (int)(ent[k] >> 32);
                    ovf_d[o] = (b << BIN_SHIFT) | l;
                    ovf_s[o] = (int)((ent[k] >> 16) & 0xFFFFu);
                    ovf_w[o] = __uint_as_float(((unsigned)ent[k] & 0xFFFFu) << 16);
                }
            }
        }
    }
    __syncthreads();
    #pragma unroll
    for (int k = 0; k < EPB / T1; ++k) {           // grouped streaming write-out
        int idx = k * T1 + t;
        if (idx < cnt_blk) {
            unsigned g = gaddr[idx];
            if (g != 0xFFFFFFFFu) binned[g] = stage[idx];
        }
    }
}

// ---- fast path kernel 3: per-bin LDS counting sort -> compact CSR ----
__global__ void __launch_bounds__(256)
sort_kernel(const unsigned long long* __restrict__ binned, const int* __restrict__ bin_cursor,
            unsigned* __restrict__ csr, int* __restrict__ offs, int* __restrict__ deg,
            int N, int NB) {
    __shared__ unsigned hist[NODES_PER_BIN];
    __shared__ unsigned tmp[NODES_PER_BIN];
    __shared__ unsigned cur[NODES_PER_BIN];
    int b = blockIdx.x;
    int t = threadIdx.x;
    int cnt = min(bin_cursor[b], BCAP);
    if (t < NODES_PER_BIN) { hist[t] = 0; cur[t] = 0; }
    __syncthreads();
    size_t base_in = (size_t)b * BCAP;
    for (int i = t; i < cnt; i += 256) {
        int l = (int)(binned[base_in + i] >> 32);
        atomicAdd(&hist[l], 1u);
    }
    __syncthreads();
    if (t < NODES_PER_BIN) tmp[t] = hist[t];
    __syncthreads();
    for (int off = 1; off < NODES_PER_BIN; off <<= 1) {
        unsigned v = 0;
        if (t < NODES_PER_BIN && t >= off) v = tmp[t - off];
        __syncthreads();
        if (t < NODES_PER_BIN) tmp[t] += v;
        __syncthreads();
    }
    if (t < NODES_PER_BIN) {
        int node = (b << BIN_SHIFT) + t;
        unsigned loff = tmp[t] - hist[t];
        if (node < N) {
            offs[node] = b * BCAP + (int)loff;
            deg[node]  = (int)hist[t];
        }
        tmp[t] = loff;                              // tmp now = local exclusive offsets
    }
    __syncthreads();
    for (int i = t; i < cnt; i += 256) {
        unsigned long long e = binned[base_in + i];
        int l = (int)(e >> 32);
        unsigned p = tmp[l] + atomicAdd(&cur[l], 1u);
        csr[base_in + p] = (unsigned)e;             // scattered, but block-private 6 KB region
    }
}

// ---- fast path kernel 4: gather (one wave/node, bf16, unroll-8) ----
__global__ void __launch_bounds__(256)
gather_kernel2(const unsigned* __restrict__ hb, const int* __restrict__ offs,
               const int* __restrict__ deg, const unsigned* __restrict__ csr,
               const int* __restrict__ bin_cursor,
               const int* __restrict__ ovf_cnt, const int* __restrict__ ovf_d,
               const int* __restrict__ ovf_s, const float* __restrict__ ovf_w,
               float* __restrict__ out, int N) {
    int node = blockIdx.x * 4 + (threadIdx.x >> 6);
    if (node >= N) return;
    int lane = threadIdx.x & 63;
    int dg = deg[node];
    int base = offs[node];
    int m = min(dg, 64);

    unsigned pu = 0;
    if (lane < m) pu = csr[base + lane];
    int mr = (m + 7) & ~7;

    float accx = 0.0f, accy = 0.0f;
    for (int j = 0; j < mr; j += 8) {
        unsigned u0 = __shfl(pu, j + 0, 64);
        unsigned u1 = __shfl(pu, j + 1, 64);
        unsigned u2 = __shfl(pu, j + 2, 64);
        unsigned u3 = __shfl(pu, j + 3, 64);
        unsigned u4 = __shfl(pu, j + 4, 64);
        unsigned u5 = __shfl(pu, j + 5, 64);
        unsigned u6 = __shfl(pu, j + 6, 64);
        unsigned u7 = __shfl(pu, j + 7, 64);
        unsigned v0 = hb[(size_t)(u0 >> 16) * 64 + lane];
        unsigned v1 = hb[(size_t)(u1 >> 16) * 64 + lane];
        unsigned v2 = hb[(size_t)(u2 >> 16) * 64 + lane];
        unsigned v3 = hb[(size_t)(u3 >> 16) * 64 + lane];
        unsigned v4 = hb[(size_t)(u4 >> 16) * 64 + lane];
        unsigned v5 = hb[(size_t)(u5 >> 16) * 64 + lane];
        unsigned v6 = hb[(size_t)(u6 >> 16) * 64 + lane];
        unsigned v7 = hb[(size_t)(u7 >> 16) * 64 + lane];
        #define ACC(u, v)                                             \
        {   float wf = __uint_as_float((u) << 16);                    \
            float vx = __uint_as_float((v) << 16);                    \
            float vy = __uint_as_float((v) & 0xffff0000u);            \
            accx += vx * wf; accy += vy * wf; }
        ACC(u0, v0) ACC(u1, v1) ACC(u2, v2) ACC(u3, v3)
        ACC(u4, v4) ACC(u5, v5) ACC(u6, v6) ACC(u7, v7)
        #undef ACC
    }
    for (int j = 64; j < dg; ++j) {    // deg > 64 (rare): uniform broadcast loads
        unsigned u = csr[base + j];
        float wf = __uint_as_float(u << 16);
        unsigned v = hb[(size_t)(u >> 16) * 64 + lane];
        accx += __uint_as_float(v << 16) * wf;
        accy += __uint_as_float(v & 0xffff0000u) * wf;
    }
    if (bin_cursor[node >> BIN_SHIFT] > BCAP) {  // bin overflowed (expected: never)
        int oc = min(*ovf_cnt, OVF_CAP);
        for (int o = 0; o < oc; ++o) {
            if (ovf_d[o] == node) {
                float we = ovf_w[o];
                unsigned v = hb[(size_t)ovf_s[o] * 64 + lane];
                accx += __uint_as_float(v << 16) * we;
                accy += __uint_as_float(v & 0xffff0000u) * we;
            }
        }
    }
    f2v r;
    r.x = accx; r.y = accy;
    __builtin_nontemporal_store(r, (f2v*)(out + (size_t)node * D_FEAT) + lane);
}

// ================== FALLBACK PATH: compact CSR (fp32, exact) ==================

__global__ void degree_kernel(const int* __restrict__ dst, int* __restrict__ deg, int E) {
    int e = blockIdx.x * blockDim.x + threadIdx.x;
    if (e >= E) return;
    atomicAdd(&deg[dst[e]], 1);
}

__global__ void scan_blocks(const int* __restrict__ deg, int* __restrict__ offs,
                            int* __restrict__ blockSums, int N) {
    __shared__ int tmp[256];
    int tid = threadIdx.x;
    int gid = blockIdx.x * 256 + tid;
    int v = (gid < N) ? deg[gid] : 0;
    tmp[tid] = v;
    __syncthreads();
    for (int off = 1; off < 256; off <<= 1) {
        int t = (tid >= off) ? tmp[tid - off] : 0;
        __syncthreads();
        tmp[tid] += t;
        __syncthreads();
    }
    if (gid < N) offs[gid] = tmp[tid] - v;
    if (tid == 255) blockSums[blockIdx.x] = tmp[255];
}

__global__ void scan_sums(int* __restrict__ blockSums, int* __restrict__ blockOffs, int nb) {
    __shared__ int tmp[256];
    int tid = threadIdx.x;
    int v = (tid < nb) ? blockSums[tid] : 0;
    tmp[tid] = v;
    __syncthreads();
    for (int off = 1; off < 256; off <<= 1) {
        int t = (tid >= off) ? tmp[tid - off] : 0;
        __syncthreads();
        tmp[tid] += t;
        __syncthreads();
    }
    if (tid < nb) blockOffs[tid] = tmp[tid] - v;
}

__global__ void scan_fixup(int* __restrict__ offs, const int* __restrict__ blockOffs,
                           int* __restrict__ cursor, int N) {
    int gid = blockIdx.x * 256 + threadIdx.x;
    if (gid >= N) return;
    int o = offs[gid] + blockOffs[blockIdx.x];
    offs[gid] = o;
    cursor[gid] = o;
}

__global__ void bucket_kernel(const int* __restrict__ src, const int* __restrict__ dst,
                              const float* __restrict__ dt, const float* __restrict__ norm,
                              const float* __restrict__ decay_lam,
                              int* __restrict__ cursor, float2* __restrict__ pairs, int E) {
    int e = blockIdx.x * blockDim.x + threadIdx.x;
    if (e >= E) return;
    float lam = fmaxf(decay_lam[0], 0.0f) + 1e-4f;
    float w = norm[e] * expf(-lam * dt[e]);
    int d = dst[e];
    int pos = atomicAdd(&cursor[d], 1);
    float2 p;
    p.x = __int_as_float(src[e]);
    p.y = w;
    pairs[pos] = p;
}

__global__ void __launch_bounds__(256)
gather_kernel(const float* __restrict__ h,
              const int* __restrict__ offs, const int* __restrict__ deg,
              const float2* __restrict__ pairs, float* __restrict__ out, int N) {
    int node = blockIdx.x * 4 + (threadIdx.x >> 6);
    if (node >= N) return;
    int lane = threadIdx.x & 63;
    int start = offs[node];
    int end = start + deg[node];
    float accx = 0.0f, accy = 0.0f;
    for (int j = start; j < end; ++j) {
        float2 p = pairs[j];
        int s = __float_as_int(p.x);
        float we = p.y;
        float2 v = ((const float2*)(h + (size_t)s * D_FEAT))[lane];
        accx += v.x * we;
        accy += v.y * we;
    }
    float2 r; r.x = accx; r.y = accy;
    ((float2*)(out + (size_t)node * D_FEAT))[lane] = r;
}

extern "C" void kernel_launch(void* const* d_in, const int* in_sizes, int n_in,
                              void* d_out, int out_size, void* d_ws, size_t ws_size,
                              hipStream_t stream) {
    const float* h         = (const float*)d_in[0];
    const int*   src       = (const int*)d_in[1];
    const int*   dst       = (const int*)d_in[2];
    const float* dt        = (const float*)d_in[3];
    const float* norm      = (const float*)d_in[4];
    const float* decay_lam = (const float*)d_in[5];
    float* out = (float*)d_out;

    const int E  = in_sizes[1];
    const int HN = in_sizes[0];
    const int N  = out_size / D_FEAT;
    const int NB = (N + NODES_PER_BIN - 1) >> BIN_SHIFT;

    auto align64 = [](size_t x) { return (x + 63) & ~(size_t)63; };
    size_t sz_binc = align64((size_t)NB * 4);
    size_t sz_ovfc = 64;
    size_t sz_ovf  = align64((size_t)OVF_CAP * 4);
    size_t sz_offs = align64((size_t)N * 4);
    size_t sz_binn = align64((size_t)NB * BCAP * 8);
    size_t sz_csr  = align64((size_t)NB * BCAP * 4);
    size_t sz_hb   = align64((size_t)HN * 2);
    size_t need = sz_binc + sz_ovfc + 3 * sz_ovf + 2 * sz_offs + sz_binn + sz_csr + sz_hb;

    if (ws_size >= need && N <= 65536 && (HN & 3) == 0) {
        char* ws = (char*)d_ws;
        int* bin_cursor = (int*)ws;                 ws += sz_binc;
        int* ovf_cnt    = (int*)ws;                 ws += sz_ovfc;
        int* ovf_d      = (int*)ws;                 ws += sz_ovf;
        int* ovf_s      = (int*)ws;                 ws += sz_ovf;
        float* ovf_w    = (float*)ws;               ws += sz_ovf;
        int* offs       = (int*)ws;                 ws += sz_offs;
        int* deg        = (int*)ws;                 ws += sz_offs;
        unsigned long long* binned = (unsigned long long*)ws;  ws += sz_binn;
        unsigned* csr   = (unsigned*)ws;            ws += sz_csr;
        unsigned* hb    = (unsigned*)ws;

        // zero bin cursors + overflow counter (contiguous, ~2 KB)
        hipMemsetAsync(bin_cursor, 0, sz_binc + sz_ovfc, stream);

        conv_kernel<<<(HN / 4 + 255) / 256, 256, 0, stream>>>(h, hb, HN / 4);
        bin_kernel<<<(E + EPB - 1) / EPB, T1, 0, stream>>>(
            src, dst, dt, norm, decay_lam, bin_cursor, binned,
            ovf_cnt, ovf_d, ovf_s, ovf_w, E, NB);
        sort_kernel<<<NB, 256, 0, stream>>>(binned, bin_cursor, csr, offs, deg, N, NB);
        gather_kernel2<<<(N + 3) / 4, 256, 0, stream>>>(
            hb, offs, deg, csr, bin_cursor, ovf_cnt, ovf_d, ovf_s, ovf_w, out, N);
    } else {
        // -------- fallback: compact CSR with hierarchical scan (fp32 exact) --------
        const int nb = (N + 255) / 256;
        char* ws = (char*)d_ws;
        int*    dega      = (int*)ws;     ws += (size_t)N * 4;
        int*    offsa     = (int*)ws;     ws += (size_t)N * 4;
        int*    cursor    = (int*)ws;     ws += (size_t)N * 4;
        int*    blockSums = (int*)ws;     ws += 256 * 4;
        int*    blockOffs = (int*)ws;     ws += 256 * 4;
        float2* pairs     = (float2*)ws;

        hipMemsetAsync(dega, 0, (size_t)N * 4, stream);
        degree_kernel<<<(E + 255) / 256, 256, 0, stream>>>(dst, dega, E);
        scan_blocks<<<nb, 256, 0, stream>>>(dega, offsa, blockSums, N);
        scan_sums<<<1, 256, 0, stream>>>(blockSums, blockOffs, nb);
        scan_fixup<<<nb, 256, 0, stream>>>(offsa, blockOffs, cursor, N);
        bucket_kernel<<<(E + 255) / 256, 256, 0, stream>>>(
            src, dst, dt, norm, decay_lam, cursor, pairs, E);
        gather_kernel<<<(N + 3) / 4, 256, 0, stream>>>(h, offsa, dega, pairs, out, N);
    }
}

// Round 12
// 128.138 us; speedup vs baseline: 1.2458x; 1.0182x over previous
//
#include <hip/hip_runtime.h>
#include <hip/hip_bf16.h>

#define D_FEAT 128
#define BIN_SHIFT 7
#define NODES_PER_BIN 128      // bin = node >> 7
#define BCAP 4096              // entries per bin region; avg ~1536 at E=600k,N=50k
#define EPB 4096               // edges per binning block
#define T1 512
#define CSR_L_CAP 5120         // 4096 + 128*7 padding slots
#define OVF_CAP 4096           // overflow side-list (expected use: 0)

typedef float f2v __attribute__((ext_vector_type(2)));

// round-to-nearest-even fp32 -> bf16 bits
__device__ __forceinline__ unsigned bf16_rne(float f) {
    unsigned u = __float_as_uint(f);
    return (u + 0x7fffu + ((u >> 16) & 1u)) >> 16;
}

// ---- fast kernel 1: fused h->bf16 conversion + LDS-grouped binning ----
// Blocks [0, convBlocks): convert h (fp32) -> hb (packed bf16 pairs).
// Blocks [convBlocks, ...): bin edges by dst>>7 with LDS histogram/scan/
// reorder; one global cursor atomic per (block,bin); grouped streaming out.
__global__ void __launch_bounds__(T1)
conv_bin_kernel(const float* __restrict__ h,
                const int* __restrict__ src, const int* __restrict__ dst,
                const float* __restrict__ dt, const float* __restrict__ norm,
                const float* __restrict__ decay_lam,
                unsigned* __restrict__ hb,
                int* __restrict__ bin_cursor, unsigned long long* __restrict__ binned,
                int* __restrict__ ovf_cnt, int* __restrict__ ovf_d,
                int* __restrict__ ovf_s, float* __restrict__ ovf_w,
                int E, int HN4, int convBlocks, int NB) {
    __shared__ unsigned hist[T1];
    __shared__ unsigned tmp[T1];
    __shared__ unsigned cur[T1];
    __shared__ unsigned gbase[T1];
    __shared__ unsigned long long stage[EPB];
    __shared__ unsigned gaddr[EPB];

    int t = threadIdx.x;
    if (blockIdx.x < convBlocks) {
        int i = blockIdx.x * T1 + t;
        if (i < HN4) {
            float4 v = ((const float4*)h)[i];
            ((uint2*)hb)[i] = make_uint2(bf16_rne(v.x) | (bf16_rne(v.y) << 16),
                                         bf16_rne(v.z) | (bf16_rne(v.w) << 16));
        }
        return;
    }

    int e0 = (blockIdx.x - convBlocks) * EPB;
    int cnt_blk = min(EPB, E - e0);

    hist[t] = 0; cur[t] = 0; gbase[t] = 0;
    __syncthreads();

    float lam = fmaxf(decay_lam[0], 0.0f) + 1e-4f;

    unsigned long long ent[EPB / T1];
    int bn[EPB / T1];
    #pragma unroll
    for (int k = 0; k < EPB / T1; ++k) {
        int e = e0 + k * T1 + t;
        bn[k] = -1;
        if (e < E) {
            int s = src[e], d = dst[e];
            float w = norm[e] * expf(-lam * dt[e]);
            int b = d >> BIN_SHIFT;
            int l = d & (NODES_PER_BIN - 1);
            ent[k] = ((unsigned long long)l << 32) | (((unsigned)s << 16) | bf16_rne(w));
            bn[k] = b;
            atomicAdd(&hist[b], 1u);
        }
    }
    __syncthreads();
    tmp[t] = hist[t];
    __syncthreads();
    for (int off = 1; off < T1; off <<= 1) {       // inclusive scan
        unsigned v = (t >= off) ? tmp[t - off] : 0;
        __syncthreads();
        tmp[t] += v;
        __syncthreads();
    }
    unsigned base_t = tmp[t] - hist[t];
    if (t < NB && hist[t] > 0)
        gbase[t] = (unsigned)atomicAdd(&bin_cursor[t], (int)hist[t]);
    __syncthreads();
    tmp[t] = base_t;
    __syncthreads();

    #pragma unroll
    for (int k = 0; k < EPB / T1; ++k) {
        if (bn[k] >= 0) {
            int b = bn[k];
            unsigned loc = atomicAdd(&cur[b], 1u);
            unsigned p = tmp[b] + loc;
            unsigned gp = gbase[b] + loc;
            stage[p] = ent[k];
            if (gp < BCAP) {
                gaddr[p] = (unsigned)b * BCAP + gp;
            } else {                               // bin region full (expected: never)
                gaddr[p] = 0xFFFFFFFFu;
                int o = atomicAdd(ovf_cnt, 1);
                if (o < OVF_CAP) {
                    int l = (int)(ent[k] >> 32);
                    ovf_d[o] = (b << BIN_SHIFT) | l;
                    ovf_s[o] = (int)((ent[k] >> 16) & 0xFFFFu);
                    ovf_w[o] = __uint_as_float(((unsigned)ent[k] & 0xFFFFu) << 16);
                }
            }
        }
    }
    __syncthreads();
    #pragma unroll
    for (int k = 0; k < EPB / T1; ++k) {           // grouped streaming write-out
        int idx = k * T1 + t;
        if (idx < cnt_blk) {
            unsigned g = gaddr[idx];
            if (g != 0xFFFFFFFFu) binned[g] = stage[idx];
        }
    }
}

// ---- fast kernel 2: fused per-bin LDS counting-sort + gather ----
// One block per bin. Bin entries -> registers -> LDS padded CSR (counts
// rounded to x8, zero-padded: src 0 / w +0 are no-op edges). Then 8 waves
// gather the bin's 128 nodes straight from LDS; 8 independent hb row loads
// in flight per batch; each output row written exactly once.
__global__ void __launch_bounds__(T1)
sort_gather_kernel(const unsigned long long* __restrict__ binned,
                   const int* __restrict__ bin_cursor,
                   const unsigned* __restrict__ hb,
                   const int* __restrict__ ovf_cnt, const int* __restrict__ ovf_d,
                   const int* __restrict__ ovf_s, const float* __restrict__ ovf_w,
                   float* __restrict__ out, int N) {
    __shared__ unsigned hist[NODES_PER_BIN];
    __shared__ unsigned padoff[NODES_PER_BIN];
    __shared__ unsigned cur[NODES_PER_BIN];
    __shared__ unsigned csr_l[CSR_L_CAP];

    int b = blockIdx.x;
    int t = threadIdx.x;
    int cnt = min(bin_cursor[b], BCAP);

    if (t < NODES_PER_BIN) { hist[t] = 0; cur[t] = 0; }
    for (int i = t; i < CSR_L_CAP; i += T1) csr_l[i] = 0;  // pad slots = no-op edges
    __syncthreads();

    // load bin entries into registers + LDS histogram
    unsigned long long ent[BCAP / T1];
    size_t base_in = (size_t)b * BCAP;
    #pragma unroll
    for (int k = 0; k < BCAP / T1; ++k) {
        int idx = k * T1 + t;
        ent[k] = ~0ull;
        if (idx < cnt) {
            unsigned long long e = binned[base_in + idx];
            ent[k] = e;
            atomicAdd(&hist[(int)(e >> 32)], 1u);
        }
    }
    __syncthreads();

    // exclusive scan of padded counts ((hist+7)&~7)
    unsigned pc = 0;
    if (t < NODES_PER_BIN) { pc = (hist[t] + 7u) & ~7u; padoff[t] = pc; }
    __syncthreads();
    for (int off = 1; off < NODES_PER_BIN; off <<= 1) {
        unsigned v = 0;
        if (t < NODES_PER_BIN && t >= off) v = padoff[t - off];
        __syncthreads();
        if (t < NODES_PER_BIN) padoff[t] += v;
        __syncthreads();
    }
    if (t < NODES_PER_BIN) padoff[t] -= pc;       // exclusive
    __syncthreads();

    // reorder into LDS padded CSR
    #pragma unroll
    for (int k = 0; k < BCAP / T1; ++k) {
        if (ent[k] != ~0ull) {
            int l = (int)(ent[k] >> 32);
            unsigned p = padoff[l] + atomicAdd(&cur[l], 1u);
            csr_l[p] = (unsigned)ent[k];
        }
    }
    __syncthreads();

    // gather: 8 waves, nodes strided by 8
    int wid = t >> 6;
    int lane = t & 63;
    int nodes = min(NODES_PER_BIN, N - (b << BIN_SHIFT));
    bool ovf_bin = bin_cursor[b] > BCAP;

    for (int l = wid; l < nodes; l += 8) {
        unsigned base = padoff[l];
        unsigned mr = (hist[l] + 7u) & ~7u;
        float accx = 0.0f, accy = 0.0f;
        for (unsigned j = 0; j < mr; j += 8) {
            unsigned u0 = csr_l[base + j + 0];
            unsigned u1 = csr_l[base + j + 1];
            unsigned u2 = csr_l[base + j + 2];
            unsigned u3 = csr_l[base + j + 3];
            unsigned u4 = csr_l[base + j + 4];
            unsigned u5 = csr_l[base + j + 5];
            unsigned u6 = csr_l[base + j + 6];
            unsigned u7 = csr_l[base + j + 7];
            unsigned v0 = hb[(size_t)(u0 >> 16) * 64 + lane];
            unsigned v1 = hb[(size_t)(u1 >> 16) * 64 + lane];
            unsigned v2 = hb[(size_t)(u2 >> 16) * 64 + lane];
            unsigned v3 = hb[(size_t)(u3 >> 16) * 64 + lane];
            unsigned v4 = hb[(size_t)(u4 >> 16) * 64 + lane];
            unsigned v5 = hb[(size_t)(u5 >> 16) * 64 + lane];
            unsigned v6 = hb[(size_t)(u6 >> 16) * 64 + lane];
            unsigned v7 = hb[(size_t)(u7 >> 16) * 64 + lane];
            #define ACC(u, v)                                             \
            {   float wf = __uint_as_float((u) << 16);                    \
                float vx = __uint_as_float((v) << 16);                    \
                float vy = __uint_as_float((v) & 0xffff0000u);            \
                accx += vx * wf; accy += vy * wf; }
            ACC(u0, v0) ACC(u1, v1) ACC(u2, v2) ACC(u3, v3)
            ACC(u4, v4) ACC(u5, v5) ACC(u6, v6) ACC(u7, v7)
            #undef ACC
        }
        int node = (b << BIN_SHIFT) + l;
        if (ovf_bin) {                             // expected: never
            int oc = min(*ovf_cnt, OVF_CAP);
            for (int o = 0; o < oc; ++o) {
                if (ovf_d[o] == node) {
                    float we = ovf_w[o];
                    unsigned v = hb[(size_t)ovf_s[o] * 64 + lane];
                    accx += __uint_as_float(v << 16) * we;
                    accy += __uint_as_float(v & 0xffff0000u) * we;
                }
            }
        }
        f2v r;
        r.x = accx; r.y = accy;
        __builtin_nontemporal_store(r, (f2v*)(out + (size_t)node * D_FEAT) + lane);
    }
}

// ================== FALLBACK PATH: compact CSR (fp32, exact) ==================

__global__ void degree_kernel(const int* __restrict__ dst, int* __restrict__ deg, int E) {
    int e = blockIdx.x * blockDim.x + threadIdx.x;
    if (e >= E) return;
    atomicAdd(&deg[dst[e]], 1);
}

__global__ void scan_blocks(const int* __restrict__ deg, int* __restrict__ offs,
                            int* __restrict__ blockSums, int N) {
    __shared__ int tmp[256];
    int tid = threadIdx.x;
    int gid = blockIdx.x * 256 + tid;
    int v = (gid < N) ? deg[gid] : 0;
    tmp[tid] = v;
    __syncthreads();
    for (int off = 1; off < 256; off <<= 1) {
        int t = (tid >= off) ? tmp[tid - off] : 0;
        __syncthreads();
        tmp[tid] += t;
        __syncthreads();
    }
    if (gid < N) offs[gid] = tmp[tid] - v;
    if (tid == 255) blockSums[blockIdx.x] = tmp[255];
}

__global__ void scan_sums(int* __restrict__ blockSums, int* __restrict__ blockOffs, int nb) {
    __shared__ int tmp[256];
    int tid = threadIdx.x;
    int v = (tid < nb) ? blockSums[tid] : 0;
    tmp[tid] = v;
    __syncthreads();
    for (int off = 1; off < 256; off <<= 1) {
        int t = (tid >= off) ? tmp[tid - off] : 0;
        __syncthreads();
        tmp[tid] += t;
        __syncthreads();
    }
    if (tid < nb) blockOffs[tid] = tmp[tid] - v;
}

__global__ void scan_fixup(int* __restrict__ offs, const int* __restrict__ blockOffs,
                           int* __restrict__ cursor, int N) {
    int gid = blockIdx.x * 256 + threadIdx.x;
    if (gid >= N) return;
    int o = offs[gid] + blockOffs[blockIdx.x];
    offs[gid] = o;
    cursor[gid] = o;
}

__global__ void bucket_kernel(const int* __restrict__ src, const int* __restrict__ dst,
                              const float* __restrict__ dt, const float* __restrict__ norm,
                              const float* __restrict__ decay_lam,
                              int* __restrict__ cursor, float2* __restrict__ pairs, int E) {
    int e = blockIdx.x * blockDim.x + threadIdx.x;
    if (e >= E) return;
    float lam = fmaxf(decay_lam[0], 0.0f) + 1e-4f;
    float w = norm[e] * expf(-lam * dt[e]);
    int d = dst[e];
    int pos = atomicAdd(&cursor[d], 1);
    float2 p;
    p.x = __int_as_float(src[e]);
    p.y = w;
    pairs[pos] = p;
}

__global__ void __launch_bounds__(256)
gather_kernel(const float* __restrict__ h,
              const int* __restrict__ offs, const int* __restrict__ deg,
              const float2* __restrict__ pairs, float* __restrict__ out, int N) {
    int node = blockIdx.x * 4 + (threadIdx.x >> 6);
    if (node >= N) return;
    int lane = threadIdx.x & 63;
    int start = offs[node];
    int end = start + deg[node];
    float accx = 0.0f, accy = 0.0f;
    for (int j = start; j < end; ++j) {
        float2 p = pairs[j];
        int s = __float_as_int(p.x);
        float we = p.y;
        float2 v = ((const float2*)(h + (size_t)s * D_FEAT))[lane];
        accx += v.x * we;
        accy += v.y * we;
    }
    float2 r; r.x = accx; r.y = accy;
    ((float2*)(out + (size_t)node * D_FEAT))[lane] = r;
}

extern "C" void kernel_launch(void* const* d_in, const int* in_sizes, int n_in,
                              void* d_out, int out_size, void* d_ws, size_t ws_size,
                              hipStream_t stream) {
    const float* h         = (const float*)d_in[0];
    const int*   src       = (const int*)d_in[1];
    const int*   dst       = (const int*)d_in[2];
    const float* dt        = (const float*)d_in[3];
    const float* norm      = (const float*)d_in[4];
    const float* decay_lam = (const float*)d_in[5];
    float* out = (float*)d_out;

    const int E  = in_sizes[1];
    const int HN = in_sizes[0];
    const int N  = out_size / D_FEAT;
    const int NB = (N + NODES_PER_BIN - 1) >> BIN_SHIFT;

    auto align64 = [](size_t x) { return (x + 63) & ~(size_t)63; };
    size_t sz_binc = align64((size_t)NB * 4);
    size_t sz_ovfc = 64;
    size_t sz_ovf  = align64((size_t)OVF_CAP * 4);
    size_t sz_binn = align64((size_t)NB * BCAP * 8);
    size_t sz_hb   = align64((size_t)HN * 2);
    size_t need = sz_binc + sz_ovfc + 3 * sz_ovf + sz_binn + sz_hb;

    if (ws_size >= need && N <= 65536 && (HN & 3) == 0 && NB <= T1) {
        char* ws = (char*)d_ws;
        int* bin_cursor = (int*)ws;                 ws += sz_binc;
        int* ovf_cnt    = (int*)ws;                 ws += sz_ovfc;
        int* ovf_d      = (int*)ws;                 ws += sz_ovf;
        int* ovf_s      = (int*)ws;                 ws += sz_ovf;
        float* ovf_w    = (float*)ws;               ws += sz_ovf;
        unsigned long long* binned = (unsigned long long*)ws;  ws += sz_binn;
        unsigned* hb    = (unsigned*)ws;

        hipMemsetAsync(bin_cursor, 0, sz_binc + sz_ovfc, stream);

        const int HN4 = HN / 4;
        const int convBlocks = (HN4 + T1 - 1) / T1;
        const int binBlocks  = (E + EPB - 1) / EPB;
        conv_bin_kernel<<<convBlocks + binBlocks, T1, 0, stream>>>(
            h, src, dst, dt, norm, decay_lam, hb, bin_cursor, binned,
            ovf_cnt, ovf_d, ovf_s, ovf_w, E, HN4, convBlocks, NB);

        sort_gather_kernel<<<NB, T1, 0, stream>>>(
            binned, bin_cursor, hb, ovf_cnt, ovf_d, ovf_s, ovf_w, out, N);
    } else {
        // -------- fallback: compact CSR with hierarchical scan (fp32 exact) --------
        const int nb = (N + 255) / 256;
        char* ws = (char*)d_ws;
        int*    dega      = (int*)ws;     ws += (size_t)N * 4;
        int*    offsa     = (int*)ws;     ws += (size_t)N * 4;
        int*    cursor    = (int*)ws;     ws += (size_t)N * 4;
        int*    blockSums = (int*)ws;     ws += 256 * 4;
        int*    blockOffs = (int*)ws;     ws += 256 * 4;
        float2* pairs     = (float2*)ws;

        hipMemsetAsync(dega, 0, (size_t)N * 4, stream);
        degree_kernel<<<(E + 255) / 256, 256, 0, stream>>>(dst, dega, E);
        scan_blocks<<<nb, 256, 0, stream>>>(dega, offsa, blockSums, N);
        scan_sums<<<1, 256, 0, stream>>>(blockSums, blockOffs, nb);
        scan_fixup<<<nb, 256, 0, stream>>>(offsa, blockOffs, cursor, N);
        bucket_kernel<<<(E + 255) / 256, 256, 0, stream>>>(
            src, dst, dt, norm, decay_lam, cursor, pairs, E);
        gather_kernel<<<(N + 3) / 4, 256, 0, stream>>>(h, offsa, dega, pairs, out, N);
    }
}